// Round 5
// baseline (2706.434 us; speedup 1.0000x reference)
//
#include <hip/hip_runtime.h>
#include <cstdint>
#include <cstddef>

typedef unsigned short ushort_t;
typedef unsigned int uint_t;

#define B_ 16
#define N_ 4096
#define S_ 1024
#define K_ 32
#define NR 524288    // B*S*K rows
#define NQ 16384     // B*S queries
#define NWAVES 8192  // NR / 64

// DT: 1 = bf16 buffers, 0 = fp32 buffers
#define DT_BF16 1
#define DT_FP32 0

__device__ __forceinline__ float bf2f(ushort_t u) {
    union { uint_t i; float f; } x; x.i = ((uint_t)u) << 16; return x.f;
}
__device__ __forceinline__ ushort_t f2bf(float f) {
    union { float f; uint_t u; } x; x.f = f;
    uint_t u = x.u;
    uint_t r = (u + 0x7fffu + ((u >> 16) & 1u)) >> 16;   // RNE
    return (ushort_t)r;
}

template <int DT>
__device__ __forceinline__ float ldx(const void* p, size_t i) {
    if (DT) return bf2f(((const ushort_t*)p)[i]);
    else    return ((const float*)p)[i];
}
template <int DT>
__device__ __forceinline__ void stx(void* p, size_t i, float v) {
    if (DT) ((ushort_t*)p)[i] = f2bf(v);
    else    ((float*)p)[i] = v;
}

// ---------------------------------------------------------------------------
// detect: bf16 (flag=1) vs fp32 (flag=0) inputs, from exponent-field stats.
// ---------------------------------------------------------------------------
__global__ void detect_kernel(const uint_t* __restrict__ xyz, int* __restrict__ flag) {
    if (threadIdx.x == 0 && blockIdx.x == 0) {
        int hits = 0;
        for (int i = 0; i < 256; i++) {
            uint_t lo = xyz[i] & 0xffffu;
            int e = (int)((lo >> 7) & 0xffu);
            if (e >= 117 && e <= 131) hits++;
        }
        *flag = (hits >= 128) ? 1 : 0;
    }
}

// ---------------------------------------------------------------------------
// prep: weights -> fp32 transposed. wt0[c][64], wt1[c][64], wt2[c][128]
// ---------------------------------------------------------------------------
template <int DT>
__global__ __launch_bounds__(256) void prep_kernel(
        const void* __restrict__ W0, const void* __restrict__ W1,
        const void* __restrict__ W2,
        float* __restrict__ wt0, float* __restrict__ wt1, float* __restrict__ wt2,
        const int* __restrict__ flag) {
    if (*flag != DT) return;
    int tid = threadIdx.x;
    for (int i = tid; i < 64 * 67; i += 256) { int o = i / 67, c = i % 67; wt0[c * 64 + o] = ldx<DT>(W0, i); }
    for (int i = tid; i < 64 * 64; i += 256) { int o = i >> 6, c = i & 63; wt1[c * 64 + o] = ldx<DT>(W1, i); }
    for (int i = tid; i < 128 * 64; i += 256) { int o = i >> 6, c = i & 63; wt2[c * 128 + o] = ldx<DT>(W2, i); }
}

// ---------------------------------------------------------------------------
// FPS: one block (256 thr = 4 waves) per batch, 16 pts/thread in VGPRs.
// NO global stores inside the loop (far history kept in LDS; outputs written
// in a coalesced epilogue) -> the per-iteration barrier drains LDS only.
// Tree-structured local argmax (adjacent pairing => first-index tie-break).
// Exact ref arithmetic (fp contract off), np.argmax semantics.
// ---------------------------------------------------------------------------
template <int DT>
__global__ __launch_bounds__(256) void fps_kernel(
        const void* __restrict__ xyz, float* __restrict__ qxyz,
        void* __restrict__ out_sxyz, const int* __restrict__ flag) {
    #pragma clang fp contract(off)
    if (*flag != DT) return;
    __shared__ float xs[N_], ys[N_], zs[N_];
    __shared__ float2 cand[2][4];
    __shared__ int farh[S_];
    int b = blockIdx.x, tid = threadIdx.x;
    int wv = tid >> 6, lane = tid & 63;
    size_t base = (size_t)b * N_ * 3;

    float px[16], py[16], pz[16], dist[16];
    #pragma unroll
    for (int t = 0; t < 16; t++) {
        int p = tid + t * 256;
        float x = ldx<DT>(xyz, base + p * 3 + 0);
        float y = ldx<DT>(xyz, base + p * 3 + 1);
        float z = ldx<DT>(xyz, base + p * 3 + 2);
        px[t] = x; py[t] = y; pz[t] = z;
        xs[p] = x; ys[p] = y; zs[p] = z;
        dist[t] = 1e10f;
    }
    __syncthreads();

    int far = 0;
    for (int i = 0; i < S_; i++) {
        float cx = xs[far], cy = ys[far], cz = zs[far];
        if (tid == 0) farh[i] = far;
        // dist update (independent) then 4-level tree argmax.
        #pragma unroll
        for (int t = 0; t < 16; t++) {
            float dx = px[t] - cx, dy = py[t] - cy, dz = pz[t] - cz;
            float d = (dx * dx + dy * dy) + dz * dz;   // matches ref sum order
            dist[t] = fminf(dist[t], d);
        }
        float v8[8]; int i8[8];
        #pragma unroll
        for (int t = 0; t < 8; t++) {
            bool s = dist[2 * t + 1] > dist[2 * t];    // strict: lower t wins tie
            v8[t] = s ? dist[2 * t + 1] : dist[2 * t];
            i8[t] = s ? 2 * t + 1 : 2 * t;
        }
        float v4[4]; int i4[4];
        #pragma unroll
        for (int t = 0; t < 4; t++) {
            bool s = v8[2 * t + 1] > v8[2 * t];
            v4[t] = s ? v8[2 * t + 1] : v8[2 * t];
            i4[t] = s ? i8[2 * t + 1] : i8[2 * t];
        }
        float v2[2]; int i2[2];
        #pragma unroll
        for (int t = 0; t < 2; t++) {
            bool s = v4[2 * t + 1] > v4[2 * t];
            v2[t] = s ? v4[2 * t + 1] : v4[2 * t];
            i2[t] = s ? i4[2 * t + 1] : i4[2 * t];
        }
        bool s0 = v2[1] > v2[0];
        float bv = s0 ? v2[1] : v2[0];
        int bi = tid + (s0 ? i2[1] : i2[0]) * 256;
        // wave argmax (64 lanes)
        #pragma unroll
        for (int off = 32; off >= 1; off >>= 1) {
            float ov = __shfl_down(bv, off);
            int   oi = __shfl_down(bi, off);
            if (ov > bv || (ov == bv && oi < bi)) { bv = ov; bi = oi; }
        }
        int buf = i & 1;
        if (lane == 0) cand[buf][wv] = make_float2(bv, __int_as_float(bi));
        __syncthreads();
        float2 c0 = cand[buf][0];
        float fv = c0.x; int fi = __float_as_int(c0.y);
        #pragma unroll
        for (int w2 = 1; w2 < 4; w2++) {
            float2 cw = cand[buf][w2];
            int oi = __float_as_int(cw.y);
            if (cw.x > fv || (cw.x == fv && oi < fi)) { fv = cw.x; fi = oi; }
        }
        far = fi;
    }
    __syncthreads();
    // epilogue: emit all centroids (fp32 for knn, DT for output 0)
    for (int i = tid; i < S_; i += 256) {
        int f = farh[i];
        float cx = xs[f], cy = ys[f], cz = zs[f];
        int qi = b * S_ + i;
        qxyz[qi * 3 + 0] = cx; qxyz[qi * 3 + 1] = cy; qxyz[qi * 3 + 2] = cz;
        stx<DT>(out_sxyz, (size_t)qi * 3 + 0, cx);
        stx<DT>(out_sxyz, (size_t)qi * 3 + 1, cy);
        stx<DT>(out_sxyz, (size_t)qi * 3 + 2, cz);
    }
}

// ---------------------------------------------------------------------------
// KNN: one wave per query -> 32 neighbor indices. Exact reference distance.
// ---------------------------------------------------------------------------
template <int DT>
__global__ __launch_bounds__(64) void knn_kernel(
        const void* __restrict__ xyz, const float* __restrict__ qxyz,
        int* __restrict__ nbr, const int* __restrict__ flag) {
    #pragma clang fp contract(off)
    if (*flag != DT) return;
    __shared__ float dsm[N_];
    int bs = blockIdx.x;
    int b = bs >> 10;
    int lane = threadIdx.x;
    size_t xb = (size_t)b * N_ * 3;

    float qx = qxyz[bs * 3 + 0], qy = qxyz[bs * 3 + 1], qz = qxyz[bs * 3 + 2];
    float qq = (qx * qx + qy * qy) + qz * qz;

    const float FINF = __builtin_inff();
    float lv = FINF; int li = 0;
    for (int s = 0; s < 64; s++) {
        int p = s * 64 + lane;
        float x = ldx<DT>(xyz, xb + p * 3 + 0);
        float y = ldx<DT>(xyz, xb + p * 3 + 1);
        float z = ldx<DT>(xyz, xb + p * 3 + 2);
        float pp = (x * x + y * y) + z * z;
        float dt = (qx * x + qy * y) + qz * z;
        float d = (qq + pp) - 2.0f * dt;               // matches ref
        dsm[s * 64 + ((lane + s) & 63)] = d;           // swizzled store
        if (d < lv) { lv = d; li = p; }
    }
    __syncthreads();

    unsigned long long mask = 0ull;   // consumed rows of MY column
    int my_nbr = 0;
    for (int r = 0; r < K_; r++) {
        float v = lv; int idx = li;
        #pragma unroll
        for (int off = 32; off >= 1; off >>= 1) {
            float ov = __shfl_down(v, off);
            int   oi = __shfl_down(idx, off);
            if (ov < v || (ov == v && oi < idx)) { v = ov; idx = oi; }
        }
        idx = __shfl(idx, 0);
        int glane = idx & 63;
        if (lane == r) my_nbr = idx;
        if (lane == glane) mask |= 1ull << (idx >> 6);
        unsigned long long gm = __shfl(mask, glane);
        // refresh glane's column min over unconsumed entries (lane = s index)
        float v2 = ((gm >> lane) & 1ull) ? FINF : dsm[lane * 64 + ((glane + lane) & 63)];
        int i2 = lane * 64 + glane;
        #pragma unroll
        for (int off = 32; off >= 1; off >>= 1) {
            float ov = __shfl_down(v2, off);
            int   oi = __shfl_down(i2, off);
            if (ov < v2 || (ov == v2 && oi < i2)) { v2 = ov; i2 = oi; }
        }
        v2 = __shfl(v2, 0); i2 = __shfl(i2, 0);
        if (lane == glane) { lv = v2; li = i2; }
    }
    if (lane < K_) nbr[bs * K_ + lane] = my_nbr;
}

// ---------------------------------------------------------------------------
// L0: one thread per row. Vectorized feature gather + 67x64 FMA -> yT bf16.
// ---------------------------------------------------------------------------
template <int DT>
__global__ __launch_bounds__(256) void l0_kernel(
        const void* __restrict__ xyz, const void* __restrict__ fea,
        const float* __restrict__ qxyz, const int* __restrict__ nbr,
        const float* __restrict__ wt0, ushort_t* __restrict__ yT,
        const int* __restrict__ flag) {
    if (*flag != DT) return;
    int row = blockIdx.x * 256 + threadIdx.x;
    int bs = row >> 5, b = bs >> 10;
    int p = nbr[row];
    p = (p < 0) ? 0 : (p > N_ - 1 ? N_ - 1 : p);       // defensive clamp
    float qx = qxyz[bs * 3 + 0], qy = qxyz[bs * 3 + 1], qz = qxyz[bs * 3 + 2];
    size_t xb = ((size_t)b * N_ + p) * 3;
    float dx = ldx<DT>(xyz, xb + 0) - qx;
    float dy = ldx<DT>(xyz, xb + 1) - qy;
    float dz = ldx<DT>(xyz, xb + 2) - qz;

    float acc[64];
    #pragma unroll
    for (int o = 0; o < 64; o++)
        acc[o] = fmaf(dz, wt0[128 + o], fmaf(dy, wt0[64 + o], dx * wt0[o]));

    size_t fb = ((size_t)b * N_ + p) * 64;
    if (DT) {
        const uint4* fr = (const uint4*)((const ushort_t*)fea + fb);
        #pragma unroll 2
        for (int i = 0; i < 8; i++) {
            uint4 u = fr[i];
            uint_t ua[4] = { u.x, u.y, u.z, u.w };
            #pragma unroll
            for (int j = 0; j < 4; j++) {
                float x0 = bf2f((ushort_t)(ua[j] & 0xffffu));
                float x1 = bf2f((ushort_t)(ua[j] >> 16));
                const float* w = wt0 + (3 + i * 8 + j * 2) * 64;
                #pragma unroll
                for (int o = 0; o < 64; o++) acc[o] = fmaf(x0, w[o], acc[o]);
                #pragma unroll
                for (int o = 0; o < 64; o++) acc[o] = fmaf(x1, w[64 + o], acc[o]);
            }
        }
    } else {
        const float4* fr = (const float4*)((const float*)fea + fb);
        #pragma unroll 2
        for (int i = 0; i < 16; i++) {
            float4 u = fr[i];
            float ua[4] = { u.x, u.y, u.z, u.w };
            #pragma unroll
            for (int j = 0; j < 4; j++) {
                const float* w = wt0 + (3 + i * 4 + j) * 64;
                #pragma unroll
                for (int o = 0; o < 64; o++) acc[o] = fmaf(ua[j], w[o], acc[o]);
            }
        }
    }
    #pragma unroll
    for (int o = 0; o < 64; o++)
        yT[(size_t)o * NR + row] = f2bf(acc[o]);
}

// ---------------------------------------------------------------------------
// BN stats over 64-channel channel-major bf16 buffer (dtype-independent).
// ---------------------------------------------------------------------------
__global__ __launch_bounds__(256) void stats_pass(
        const ushort_t* __restrict__ y, float* __restrict__ part) {
    int cb = blockIdx.x;
    int c = cb >> 5, ch = cb & 31;
    const uint4* src = (const uint4*)(y + (size_t)c * NR + (size_t)ch * 16384);
    float s = 0.0f, q = 0.0f;
    for (int i = threadIdx.x; i < 2048; i += 256) {
        uint4 u = src[i];
        uint_t ua[4] = { u.x, u.y, u.z, u.w };
        #pragma unroll
        for (int j = 0; j < 4; j++) {
            float v0 = bf2f((ushort_t)(ua[j] & 0xffffu));
            float v1 = bf2f((ushort_t)(ua[j] >> 16));
            s += v0; q = fmaf(v0, v0, q);
            s += v1; q = fmaf(v1, v1, q);
        }
    }
    __shared__ float ls[256], lq[256];
    int tid = threadIdx.x;
    ls[tid] = s; lq[tid] = q;
    __syncthreads();
    for (int off = 128; off >= 1; off >>= 1) {
        if (tid < off) { ls[tid] += ls[tid + off]; lq[tid] += lq[tid + off]; }
        __syncthreads();
    }
    if (tid == 0) { part[cb * 2 + 0] = ls[0]; part[cb * 2 + 1] = lq[0]; }
}

template <int DT>
__global__ __launch_bounds__(64) void stats_fin(
        const float* __restrict__ part, const void* __restrict__ g,
        const void* __restrict__ be, float* __restrict__ ab,
        const int* __restrict__ flag) {
    if (*flag != DT) return;
    int o = threadIdx.x;  // C = 64
    double s = 0.0, q = 0.0;
    for (int ch = 0; ch < 32; ch++) {
        s += (double)part[(o * 32 + ch) * 2 + 0];
        q += (double)part[(o * 32 + ch) * 2 + 1];
    }
    double mu = s / (double)NR;
    double var = q / (double)NR - mu * mu;
    if (var < 0.0) var = 0.0;
    double a = (double)ldx<DT>(g, o) / sqrt(var + 1e-5);
    ab[o]      = (float)a;
    ab[64 + o] = (float)((double)ldx<DT>(be, o) - mu * a);
}

// ---------------------------------------------------------------------------
// L1: in-place on yT. Each thread owns one row. (dtype-independent)
// ---------------------------------------------------------------------------
__global__ __launch_bounds__(256) void l1_kernel(
        ushort_t* yT, const float* __restrict__ wt1, const float* __restrict__ ab) {
    int row = blockIdx.x * 256 + threadIdx.x;
    float xv[64];
    #pragma unroll
    for (int c = 0; c < 64; c++)
        xv[c] = fmaxf(fmaf(bf2f(yT[(size_t)c * NR + row]), ab[c], ab[64 + c]), 0.0f);
    float acc[64];
    #pragma unroll
    for (int o = 0; o < 64; o++) acc[o] = 0.0f;
    #pragma unroll 4
    for (int c = 0; c < 64; c++) {
        const float* w = wt1 + c * 64;
        #pragma unroll
        for (int o = 0; o < 64; o++) acc[o] = fmaf(xv[c], w[o], acc[o]);
    }
    #pragma unroll
    for (int o = 0; o < 64; o++)
        yT[(size_t)o * NR + row] = f2bf(acc[o]);
}

// ---------------------------------------------------------------------------
// L2 stats: recompute y2 on the fly (c-outer / o-inner: contiguous weight
// rows -> s_load_dwordx16), butterfly-reduce per channel per wave.
// part2: sums [128][NWAVES], sumsq at +128*NWAVES.
// ---------------------------------------------------------------------------
__global__ __launch_bounds__(256) void l2s_kernel(
        const ushort_t* __restrict__ yT, const float* __restrict__ wt2,
        const float* __restrict__ ab1, float* __restrict__ part2) {
    int row = blockIdx.x * 256 + threadIdx.x;
    int half = blockIdx.y;
    int lane = threadIdx.x & 63;
    int wv = blockIdx.x * 4 + (threadIdx.x >> 6);
    float xv[64];
    #pragma unroll
    for (int c = 0; c < 64; c++)
        xv[c] = fmaxf(fmaf(bf2f(yT[(size_t)c * NR + row]), ab1[c], ab1[64 + c]), 0.0f);
    float acc[64];
    #pragma unroll
    for (int o = 0; o < 64; o++) acc[o] = 0.0f;
    const float* w = wt2 + half * 64;
    #pragma unroll 4
    for (int c = 0; c < 64; c++) {
        const float* wr = w + c * 128;
        #pragma unroll
        for (int o = 0; o < 64; o++) acc[o] = fmaf(xv[c], wr[o], acc[o]);
    }
    #pragma unroll 2
    for (int o = 0; o < 64; o++) {
        float s = acc[o], q = acc[o] * acc[o];
        #pragma unroll
        for (int m = 1; m <= 32; m <<= 1) { s += __shfl_xor(s, m); q += __shfl_xor(q, m); }
        if (lane == 0) {
            int og = half * 64 + o;
            part2[og * NWAVES + wv] = s;
            part2[128 * NWAVES + og * NWAVES + wv] = q;
        }
    }
}

template <int DT>
__global__ __launch_bounds__(256) void stats2_fin(
        const float* __restrict__ part2, const void* __restrict__ g,
        const void* __restrict__ be, float* __restrict__ ab2,
        const int* __restrict__ flag) {
    if (*flag != DT) return;
    int og = blockIdx.x;  // 0..127
    float s = 0.0f, q = 0.0f;
    for (int wv = threadIdx.x; wv < NWAVES; wv += 256) {
        s += part2[og * NWAVES + wv];
        q += part2[128 * NWAVES + og * NWAVES + wv];
    }
    __shared__ float ls[256], lq[256];
    int tid = threadIdx.x;
    ls[tid] = s; lq[tid] = q;
    __syncthreads();
    for (int off = 128; off >= 1; off >>= 1) {
        if (tid < off) { ls[tid] += ls[tid + off]; lq[tid] += lq[tid + off]; }
        __syncthreads();
    }
    if (tid == 0) {
        double mu = (double)ls[0] / (double)NR;
        double var = (double)lq[0] / (double)NR - mu * mu;
        if (var < 0.0) var = 0.0;
        double a = (double)bf2f(((const ushort_t*)g)[og]);
        if (!DT) a = (double)((const float*)g)[og];
        a = a / sqrt(var + 1e-5);
        double bb = DT ? (double)bf2f(((const ushort_t*)be)[og]) : (double)((const float*)be)[og];
        ab2[og]       = (float)a;
        ab2[128 + og] = (float)(bb - mu * a);
    }
}

// ---------------------------------------------------------------------------
// fin: recompute y2 (c-outer/o-inner), BN+ReLU, maxpool over K=32 lanes.
// ---------------------------------------------------------------------------
template <int DT>
__global__ __launch_bounds__(256) void fin_kernel(
        const ushort_t* __restrict__ yT, const float* __restrict__ wt2,
        const float* __restrict__ ab1, const float* __restrict__ ab2,
        void* __restrict__ out, const int* __restrict__ flag) {
    if (*flag != DT) return;
    int row = blockIdx.x * 256 + threadIdx.x;
    int half = blockIdx.y;
    int k = row & 31, bs = row >> 5;
    float xv[64];
    #pragma unroll
    for (int c = 0; c < 64; c++)
        xv[c] = fmaxf(fmaf(bf2f(yT[(size_t)c * NR + row]), ab1[c], ab1[64 + c]), 0.0f);
    float acc[64];
    #pragma unroll
    for (int o = 0; o < 64; o++) acc[o] = 0.0f;
    const float* w = wt2 + half * 64;
    #pragma unroll 4
    for (int c = 0; c < 64; c++) {
        const float* wr = w + c * 128;
        #pragma unroll
        for (int o = 0; o < 64; o++) acc[o] = fmaf(xv[c], wr[o], acc[o]);
    }
    #pragma unroll 2
    for (int o = 0; o < 64; o++) {
        int og = half * 64 + o;
        float v = fmaxf(fmaf(acc[o], ab2[og], ab2[128 + og]), 0.0f);
        #pragma unroll
        for (int m = 1; m <= 16; m <<= 1) v = fmaxf(v, __shfl_xor(v, m));
        if (k == 0) stx<DT>(out, 49152 + (size_t)bs * 128 + og, v);
    }
}

// ---------------------------------------------------------------------------
extern "C" void kernel_launch(void* const* d_in, const int* in_sizes, int n_in,
                              void* d_out, int out_size, void* d_ws, size_t ws_size,
                              hipStream_t stream) {
    const void* xyz = d_in[0];
    const void* fea = d_in[1];
    const void* W0  = d_in[2];
    const void* g0  = d_in[4];
    const void* be0 = d_in[5];
    const void* W1  = d_in[6];
    const void* g1  = d_in[8];
    const void* be1 = d_in[9];
    const void* W2  = d_in[10];
    const void* g2  = d_in[12];
    const void* be2 = d_in[13];

    char* w = (char*)d_ws;
    // total workspace footprint: ~74.3 MB
    ushort_t* yT   = (ushort_t*)(w);                       // 67,108,864
    int*      nbr  = (int*)     (w + 67108864);            //  2,097,152
    float*    qxyz = (float*)   (w + 69206016);            //    196,608
    float*    part = (float*)   (w + 69402624);            //     16,384
    float*    part2= (float*)   (w + 69419008);            //  8,388,608
    float*    ab0  = (float*)   (w + 77807616);            //        512
    float*    ab1  = (float*)   (w + 77808128);            //        512
    float*    ab2  = (float*)   (w + 77808640);            //      1,024
    float*    wt0  = (float*)   (w + 77809664);            //     17,152
    float*    wt1  = (float*)   (w + 77826816);            //     16,384
    float*    wt2  = (float*)   (w + 77843200);            //     32,768
    int*      flag = (int*)     (w + 77875968);            //          4

    detect_kernel<<<1, 64, 0, stream>>>((const uint_t*)xyz, flag);

    prep_kernel<DT_BF16><<<1, 256, 0, stream>>>(W0, W1, W2, wt0, wt1, wt2, flag);
    prep_kernel<DT_FP32><<<1, 256, 0, stream>>>(W0, W1, W2, wt0, wt1, wt2, flag);

    fps_kernel<DT_BF16><<<B_, 256, 0, stream>>>(xyz, qxyz, d_out, flag);
    fps_kernel<DT_FP32><<<B_, 256, 0, stream>>>(xyz, qxyz, d_out, flag);

    knn_kernel<DT_BF16><<<NQ, 64, 0, stream>>>(xyz, qxyz, nbr, flag);
    knn_kernel<DT_FP32><<<NQ, 64, 0, stream>>>(xyz, qxyz, nbr, flag);

    // layer 0
    l0_kernel<DT_BF16><<<2048, 256, 0, stream>>>(xyz, fea, qxyz, nbr, wt0, yT, flag);
    l0_kernel<DT_FP32><<<2048, 256, 0, stream>>>(xyz, fea, qxyz, nbr, wt0, yT, flag);
    stats_pass<<<64 * 32, 256, 0, stream>>>(yT, part);
    stats_fin<DT_BF16><<<1, 64, 0, stream>>>(part, g0, be0, ab0, flag);
    stats_fin<DT_FP32><<<1, 64, 0, stream>>>(part, g0, be0, ab0, flag);

    // layer 1 (in-place)
    l1_kernel<<<2048, 256, 0, stream>>>(yT, wt1, ab0);
    stats_pass<<<64 * 32, 256, 0, stream>>>(yT, part);
    stats_fin<DT_BF16><<<1, 64, 0, stream>>>(part, g1, be1, ab1, flag);
    stats_fin<DT_FP32><<<1, 64, 0, stream>>>(part, g1, be1, ab1, flag);

    // layer 2: stats via recompute, then fused bn+relu+maxpool via recompute
    l2s_kernel<<<dim3(2048, 2), 256, 0, stream>>>(yT, wt2, ab1, part2);
    stats2_fin<DT_BF16><<<128, 256, 0, stream>>>(part2, g2, be2, ab2, flag);
    stats2_fin<DT_FP32><<<128, 256, 0, stream>>>(part2, g2, be2, ab2, flag);

    fin_kernel<DT_BF16><<<dim3(2048, 2), 256, 0, stream>>>(yT, wt2, ab1, ab2, d_out, flag);
    fin_kernel<DT_FP32><<<dim3(2048, 2), 256, 0, stream>>>(yT, wt2, ab1, ab2, d_out, flag);
}

// Round 7
// 1769.529 us; speedup vs baseline: 1.5295x; 1.5295x over previous
//
#include <hip/hip_runtime.h>
#include <cstdint>
#include <cstddef>

typedef unsigned short ushort_t;
typedef unsigned int uint_t;
typedef unsigned long long u64_t;

#define B_ 16
#define N_ 4096
#define S_ 1024
#define K_ 32
#define NR 524288    // B*S*K rows
#define NQ 16384     // B*S queries
#define NWAVES 8192  // NR / 64

__device__ __forceinline__ float bf2f(ushort_t u) {
    union { uint_t i; float f; } x; x.i = ((uint_t)u) << 16; return x.f;
}
__device__ __forceinline__ ushort_t f2bf(float f) {
    union { float f; uint_t u; } x; x.f = f;
    uint_t u = x.u;
    uint_t r = (u + 0x7fffu + ((u >> 16) & 1u)) >> 16;   // RNE
    return (ushort_t)r;
}

// ---------------------------------------------------------------------------
// DPP wave-64 reductions (VALU): row_shr 1/2/4/8 + row_bcast15 + row_bcast31.
// Full reduction lands in lane 63. Keys are u64 (hi,lo), unique per
// candidate -> strict compares give an exact total order (ref tie-break
// encoded in the key).
// ---------------------------------------------------------------------------
template <int CTRL>
__device__ __forceinline__ uint_t dppmov(uint_t v, uint_t idt) {
    return (uint_t)__builtin_amdgcn_update_dpp((int)idt, (int)v, CTRL, 0xF, 0xF, false);
}

__device__ __forceinline__ void wave_argmax64(uint_t& hi, uint_t& lo) {
#define STEP_MAX(C) { uint_t nh = dppmov<C>(hi, 0u); uint_t nl = dppmov<C>(lo, 0u); \
    u64_t a = ((u64_t)hi << 32) | lo, bb = ((u64_t)nh << 32) | nl; \
    if (bb > a) { hi = nh; lo = nl; } }
    STEP_MAX(0x111) STEP_MAX(0x112) STEP_MAX(0x114) STEP_MAX(0x118)
    STEP_MAX(0x142) STEP_MAX(0x143)
#undef STEP_MAX
}

__device__ __forceinline__ void wave_argmin64(uint_t& hi, uint_t& lo) {
#define STEP_MIN(C) { uint_t nh = dppmov<C>(hi, 0xFFFFFFFFu); uint_t nl = dppmov<C>(lo, 0xFFFFFFFFu); \
    u64_t a = ((u64_t)hi << 32) | lo, bb = ((u64_t)nh << 32) | nl; \
    if (bb < a) { hi = nh; lo = nl; } }
    STEP_MIN(0x111) STEP_MIN(0x112) STEP_MIN(0x114) STEP_MIN(0x118)
    STEP_MIN(0x142) STEP_MIN(0x143)
#undef STEP_MIN
}

// ---------------------------------------------------------------------------
// prep: weights fp32 -> fp32 transposed. wt0[c][64], wt1[c][64], wt2[c][128]
// ---------------------------------------------------------------------------
__global__ __launch_bounds__(256) void prep_kernel(
        const float* __restrict__ W0, const float* __restrict__ W1,
        const float* __restrict__ W2,
        float* __restrict__ wt0, float* __restrict__ wt1, float* __restrict__ wt2) {
    int tid = threadIdx.x;
    for (int i = tid; i < 64 * 67; i += 256) { int o = i / 67, c = i % 67; wt0[c * 64 + o] = W0[i]; }
    for (int i = tid; i < 64 * 64; i += 256) { int o = i >> 6, c = i & 63; wt1[c * 64 + o] = W1[i]; }
    for (int i = tid; i < 128 * 64; i += 256) { int o = i >> 6, c = i & 63; wt2[c * 128 + o] = W2[i]; }
}

// ---------------------------------------------------------------------------
// FPS: one block (4 waves) per batch, 16 pts/thread in VGPRs. Local tree
// argmax over u64 keys, DPP wave argmax, one barrier + 4-slot combine.
// Key = (dist_bits, ~p): max key == max dist, tie -> lowest p (np.argmax).
// Exact ref arithmetic (fp contract off). Centroids written straight to
// d_out (fp32 output 0); knn/l0 read them back from there.
// ---------------------------------------------------------------------------
__global__ __launch_bounds__(256) void fps_kernel(
        const float* __restrict__ xyz, float* __restrict__ out_sxyz) {
    #pragma clang fp contract(off)
    __shared__ float xs[N_], ys[N_], zs[N_];
    __shared__ uint2 cand[2][4];
    int b = blockIdx.x, tid = threadIdx.x;
    int wv = tid >> 6, lane = tid & 63;
    const float* base = xyz + (size_t)b * N_ * 3;

    float px[16], py[16], pz[16], dist[16];
    #pragma unroll
    for (int t = 0; t < 16; t++) {
        int p = tid + t * 256;
        float x = base[p * 3 + 0];
        float y = base[p * 3 + 1];
        float z = base[p * 3 + 2];
        px[t] = x; py[t] = y; pz[t] = z;
        xs[p] = x; ys[p] = y; zs[p] = z;
        dist[t] = 1e10f;
    }
    __syncthreads();

    int far = 0;
    for (int i = 0; i < S_; i++) {
        float cx = xs[far], cy = ys[far], cz = zs[far];
        if (tid == 0) {
            int qi = b * S_ + i;
            out_sxyz[qi * 3 + 0] = cx;
            out_sxyz[qi * 3 + 1] = cy;
            out_sxyz[qi * 3 + 2] = cz;
        }
        #pragma unroll
        for (int t = 0; t < 16; t++) {
            float dx = px[t] - cx, dy = py[t] - cy, dz = pz[t] - cz;
            float d = (dx * dx + dy * dy) + dz * dz;   // matches ref sum order
            dist[t] = fminf(dist[t], d);
        }
        // local tree argmax over 16 candidates via u64 keys
        uint_t kh[16], kl[16];
        #pragma unroll
        for (int t = 0; t < 16; t++) {
            kh[t] = __float_as_uint(dist[t]);          // dist >= 0: uint order = float order
            kl[t] = ~(uint_t)(tid + t * 256);
        }
        #pragma unroll
        for (int st = 8; st >= 1; st >>= 1) {
            #pragma unroll
            for (int t = 0; t < 8; t++) {
                if (t < st) {
                    u64_t a = ((u64_t)kh[t] << 32) | kl[t];
                    u64_t bb = ((u64_t)kh[t + st] << 32) | kl[t + st];
                    if (bb > a) { kh[t] = kh[t + st]; kl[t] = kl[t + st]; }
                }
            }
        }
        uint_t bh = kh[0], bl = kl[0];
        wave_argmax64(bh, bl);                  // lane 63 has wave winner
        int buf = i & 1;
        if (lane == 63) cand[buf][wv] = make_uint2(bh, bl);
        __syncthreads();
        uint2 c0 = cand[buf][0], c1 = cand[buf][1], c2 = cand[buf][2], c3 = cand[buf][3];
        u64_t best = ((u64_t)c0.x << 32) | c0.y;
        u64_t k1 = ((u64_t)c1.x << 32) | c1.y; if (k1 > best) best = k1;
        u64_t k2 = ((u64_t)c2.x << 32) | c2.y; if (k2 > best) best = k2;
        u64_t k3 = ((u64_t)c3.x << 32) | c3.y; if (k3 > best) best = k3;
        far = (int)((~(uint_t)best) & 4095u);
    }
}

// ---------------------------------------------------------------------------
// KNN: one wave per query -> 32 neighbor indices. Distances in LDS as
// sortable uints (exact float order). Per round: DPP argmin for the global
// winner, DPP argmin to refresh the winner column's cached min.
// ---------------------------------------------------------------------------
__global__ __launch_bounds__(64) void knn_kernel(
        const float* __restrict__ xyz, const float* __restrict__ qxyz,
        int* __restrict__ nbr) {
    #pragma clang fp contract(off)
    __shared__ uint_t dsm[N_];
    int bs = blockIdx.x;
    int b = bs >> 10;
    int lane = threadIdx.x;
    const float* xb = xyz + (size_t)b * N_ * 3;

    float qx = qxyz[bs * 3 + 0], qy = qxyz[bs * 3 + 1], qz = qxyz[bs * 3 + 2];
    float qq = (qx * qx + qy * qy) + qz * qz;

    uint_t ulv = 0xFFFFFFFFu; int li = 0;
    for (int s = 0; s < 64; s++) {
        int p = s * 64 + lane;
        float x = xb[p * 3 + 0];
        float y = xb[p * 3 + 1];
        float z = xb[p * 3 + 2];
        float pp = (x * x + y * y) + z * z;
        float dt = (qx * x + qy * y) + qz * z;
        float d = (qq + pp) - 2.0f * dt;               // matches ref
        uint_t ub = __float_as_uint(d);
        ub ^= (uint_t)(((int)ub >> 31)) | 0x80000000u; // sortable transform
        dsm[s * 64 + ((lane + s) & 63)] = ub;          // swizzled store
        if (ub < ulv) { ulv = ub; li = p; }            // ascending p: first wins tie
    }
    __syncthreads();

    u64_t mask = 0ull;   // consumed rows of MY column (lane = column)
    int my_nbr = 0;
    for (int r = 0; r < K_; r++) {
        uint_t hh = ulv, ll = (uint_t)li;
        wave_argmin64(hh, ll);                          // lane 63: global min
        int idx = (int)(uint_t)__builtin_amdgcn_readlane((int)ll, 63);
        int glane = idx & 63, srow = idx >> 6;
        if (lane == r) my_nbr = idx;
        if (lane == glane) mask |= 1ull << srow;
        uint_t gml = (uint_t)__builtin_amdgcn_readlane((int)(uint_t)mask, glane);
        uint_t gmh = (uint_t)__builtin_amdgcn_readlane((int)(uint_t)(mask >> 32), glane);
        u64_t gm = ((u64_t)gmh << 32) | gml;
        // refresh glane's column min over unconsumed entries (lane = row s)
        uint_t cv = ((gm >> lane) & 1ull) ? 0xFFFFFFFFu
                                          : dsm[lane * 64 + ((glane + lane) & 63)];
        uint_t ci = (uint_t)(lane * 64 + glane);
        wave_argmin64(cv, ci);
        uint_t rv = (uint_t)__builtin_amdgcn_readlane((int)cv, 63);
        uint_t ri = (uint_t)__builtin_amdgcn_readlane((int)ci, 63);
        if (lane == glane) { ulv = rv; li = (int)ri; }
    }
    if (lane < K_) nbr[bs * K_ + lane] = my_nbr;
}

// ---------------------------------------------------------------------------
// L0: one thread per row. float4 feature gather + 67x64 FMA -> yT bf16.
// ---------------------------------------------------------------------------
__global__ __launch_bounds__(256) void l0_kernel(
        const float* __restrict__ xyz, const float* __restrict__ fea,
        const float* __restrict__ qxyz, const int* __restrict__ nbr,
        const float* __restrict__ wt0, ushort_t* __restrict__ yT) {
    int row = blockIdx.x * 256 + threadIdx.x;
    int bs = row >> 5, b = bs >> 10;
    int p = nbr[row];
    p = (p < 0) ? 0 : (p > N_ - 1 ? N_ - 1 : p);
    float qx = qxyz[bs * 3 + 0], qy = qxyz[bs * 3 + 1], qz = qxyz[bs * 3 + 2];
    const float* xb = xyz + ((size_t)b * N_ + p) * 3;
    float dx = xb[0] - qx, dy = xb[1] - qy, dz = xb[2] - qz;

    float acc[64];
    #pragma unroll
    for (int o = 0; o < 64; o++)
        acc[o] = fmaf(dz, wt0[128 + o], fmaf(dy, wt0[64 + o], dx * wt0[o]));

    const float4* fr = (const float4*)(fea + ((size_t)b * N_ + p) * 64);
    #pragma unroll 2
    for (int i = 0; i < 16; i++) {
        float4 u = fr[i];
        float ua[4] = { u.x, u.y, u.z, u.w };
        #pragma unroll
        for (int j = 0; j < 4; j++) {
            const float* w = wt0 + (3 + i * 4 + j) * 64;
            #pragma unroll
            for (int o = 0; o < 64; o++) acc[o] = fmaf(ua[j], w[o], acc[o]);
        }
    }
    #pragma unroll
    for (int o = 0; o < 64; o++)
        yT[(size_t)o * NR + row] = f2bf(acc[o]);
}

// ---------------------------------------------------------------------------
// BN stats over 64-channel channel-major bf16 buffer (vectorized).
// ---------------------------------------------------------------------------
__global__ __launch_bounds__(256) void stats_pass(
        const ushort_t* __restrict__ y, float* __restrict__ part) {
    int cb = blockIdx.x;
    int c = cb >> 5, ch = cb & 31;
    const uint4* src = (const uint4*)(y + (size_t)c * NR + (size_t)ch * 16384);
    float s = 0.0f, q = 0.0f;
    for (int i = threadIdx.x; i < 2048; i += 256) {
        uint4 u = src[i];
        uint_t ua[4] = { u.x, u.y, u.z, u.w };
        #pragma unroll
        for (int j = 0; j < 4; j++) {
            float v0 = bf2f((ushort_t)(ua[j] & 0xffffu));
            float v1 = bf2f((ushort_t)(ua[j] >> 16));
            s += v0; q = fmaf(v0, v0, q);
            s += v1; q = fmaf(v1, v1, q);
        }
    }
    __shared__ float ls[256], lq[256];
    int tid = threadIdx.x;
    ls[tid] = s; lq[tid] = q;
    __syncthreads();
    for (int off = 128; off >= 1; off >>= 1) {
        if (tid < off) { ls[tid] += ls[tid + off]; lq[tid] += lq[tid + off]; }
        __syncthreads();
    }
    if (tid == 0) { part[cb * 2 + 0] = ls[0]; part[cb * 2 + 1] = lq[0]; }
}

__global__ __launch_bounds__(64) void stats_fin(
        const float* __restrict__ part, const float* __restrict__ g,
        const float* __restrict__ be, float* __restrict__ ab) {
    int o = threadIdx.x;  // C = 64
    double s = 0.0, q = 0.0;
    for (int ch = 0; ch < 32; ch++) {
        s += (double)part[(o * 32 + ch) * 2 + 0];
        q += (double)part[(o * 32 + ch) * 2 + 1];
    }
    double mu = s / (double)NR;
    double var = q / (double)NR - mu * mu;
    if (var < 0.0) var = 0.0;
    double a = (double)g[o] / sqrt(var + 1e-5);
    ab[o]      = (float)a;
    ab[64 + o] = (float)((double)be[o] - mu * a);
}

// ---------------------------------------------------------------------------
// L1: in-place on yT. Each thread owns one row.
// ---------------------------------------------------------------------------
__global__ __launch_bounds__(256) void l1_kernel(
        ushort_t* yT, const float* __restrict__ wt1, const float* __restrict__ ab) {
    int row = blockIdx.x * 256 + threadIdx.x;
    float xv[64];
    #pragma unroll
    for (int c = 0; c < 64; c++)
        xv[c] = fmaxf(fmaf(bf2f(yT[(size_t)c * NR + row]), ab[c], ab[64 + c]), 0.0f);
    float acc[64];
    #pragma unroll
    for (int o = 0; o < 64; o++) acc[o] = 0.0f;
    #pragma unroll 4
    for (int c = 0; c < 64; c++) {
        const float* w = wt1 + c * 64;
        #pragma unroll
        for (int o = 0; o < 64; o++) acc[o] = fmaf(xv[c], w[o], acc[o]);
    }
    #pragma unroll
    for (int o = 0; o < 64; o++)
        yT[(size_t)o * NR + row] = f2bf(acc[o]);
}

// ---------------------------------------------------------------------------
// L2 stats: recompute y2 on the fly (c-outer/o-inner), butterfly per wave.
// part2: sums [128][NWAVES], sumsq at +128*NWAVES.
// ---------------------------------------------------------------------------
__global__ __launch_bounds__(256) void l2s_kernel(
        const ushort_t* __restrict__ yT, const float* __restrict__ wt2,
        const float* __restrict__ ab1, float* __restrict__ part2) {
    int row = blockIdx.x * 256 + threadIdx.x;
    int half = blockIdx.y;
    int lane = threadIdx.x & 63;
    int wv = blockIdx.x * 4 + (threadIdx.x >> 6);
    float xv[64];
    #pragma unroll
    for (int c = 0; c < 64; c++)
        xv[c] = fmaxf(fmaf(bf2f(yT[(size_t)c * NR + row]), ab1[c], ab1[64 + c]), 0.0f);
    float acc[64];
    #pragma unroll
    for (int o = 0; o < 64; o++) acc[o] = 0.0f;
    const float* w = wt2 + half * 64;
    #pragma unroll 4
    for (int c = 0; c < 64; c++) {
        const float* wr = w + c * 128;
        #pragma unroll
        for (int o = 0; o < 64; o++) acc[o] = fmaf(xv[c], wr[o], acc[o]);
    }
    #pragma unroll 2
    for (int o = 0; o < 64; o++) {
        float s = acc[o], q = acc[o] * acc[o];
        #pragma unroll
        for (int m = 1; m <= 32; m <<= 1) { s += __shfl_xor(s, m); q += __shfl_xor(q, m); }
        if (lane == 0) {
            int og = half * 64 + o;
            part2[og * NWAVES + wv] = s;
            part2[128 * NWAVES + og * NWAVES + wv] = q;
        }
    }
}

__global__ __launch_bounds__(256) void stats2_fin(
        const float* __restrict__ part2, const float* __restrict__ g,
        const float* __restrict__ be, float* __restrict__ ab2) {
    int og = blockIdx.x;  // 0..127
    float s = 0.0f, q = 0.0f;
    for (int wv = threadIdx.x; wv < NWAVES; wv += 256) {
        s += part2[og * NWAVES + wv];
        q += part2[128 * NWAVES + og * NWAVES + wv];
    }
    __shared__ float ls[256], lq[256];
    int tid = threadIdx.x;
    ls[tid] = s; lq[tid] = q;
    __syncthreads();
    for (int off = 128; off >= 1; off >>= 1) {
        if (tid < off) { ls[tid] += ls[tid + off]; lq[tid] += lq[tid + off]; }
        __syncthreads();
    }
    if (tid == 0) {
        double mu = (double)ls[0] / (double)NR;
        double var = (double)lq[0] / (double)NR - mu * mu;
        if (var < 0.0) var = 0.0;
        double a = (double)g[og] / sqrt(var + 1e-5);
        ab2[og]       = (float)a;
        ab2[128 + og] = (float)((double)be[og] - mu * a);
    }
}

// ---------------------------------------------------------------------------
// fin: recompute y2 (c-outer/o-inner), BN+ReLU, maxpool over K=32 lanes,
// write fp32 feats to d_out (output 1, offset 49152 floats).
// ---------------------------------------------------------------------------
__global__ __launch_bounds__(256) void fin_kernel(
        const ushort_t* __restrict__ yT, const float* __restrict__ wt2,
        const float* __restrict__ ab1, const float* __restrict__ ab2,
        float* __restrict__ out) {
    int row = blockIdx.x * 256 + threadIdx.x;
    int half = blockIdx.y;
    int k = row & 31, bs = row >> 5;
    float xv[64];
    #pragma unroll
    for (int c = 0; c < 64; c++)
        xv[c] = fmaxf(fmaf(bf2f(yT[(size_t)c * NR + row]), ab1[c], ab1[64 + c]), 0.0f);
    float acc[64];
    #pragma unroll
    for (int o = 0; o < 64; o++) acc[o] = 0.0f;
    const float* w = wt2 + half * 64;
    #pragma unroll 4
    for (int c = 0; c < 64; c++) {
        const float* wr = w + c * 128;
        #pragma unroll
        for (int o = 0; o < 64; o++) acc[o] = fmaf(xv[c], wr[o], acc[o]);
    }
    #pragma unroll 2
    for (int o = 0; o < 64; o++) {
        int og = half * 64 + o;
        float v = fmaxf(fmaf(acc[o], ab2[og], ab2[128 + og]), 0.0f);
        #pragma unroll
        for (int m = 1; m <= 16; m <<= 1) v = fmaxf(v, __shfl_xor(v, m));
        if (k == 0) out[49152 + (size_t)bs * 128 + og] = v;
    }
}

// ---------------------------------------------------------------------------
extern "C" void kernel_launch(void* const* d_in, const int* in_sizes, int n_in,
                              void* d_out, int out_size, void* d_ws, size_t ws_size,
                              hipStream_t stream) {
    const float* xyz = (const float*)d_in[0];
    const float* fea = (const float*)d_in[1];
    const float* W0  = (const float*)d_in[2];
    const float* g0  = (const float*)d_in[4];
    const float* be0 = (const float*)d_in[5];
    const float* W1  = (const float*)d_in[6];
    const float* g1  = (const float*)d_in[8];
    const float* be1 = (const float*)d_in[9];
    const float* W2  = (const float*)d_in[10];
    const float* g2  = (const float*)d_in[12];
    const float* be2 = (const float*)d_in[13];
    float* out = (float*)d_out;

    char* w = (char*)d_ws;
    // total workspace footprint: ~74.1 MB
    ushort_t* yT   = (ushort_t*)(w);                       // 67,108,864
    int*      nbr  = (int*)     (w + 67108864);            //  2,097,152
    float*    part = (float*)   (w + 69206016);            //     16,384
    float*    part2= (float*)   (w + 69222400);            //  8,388,608
    float*    ab0  = (float*)   (w + 77611008);            //        512
    float*    ab1  = (float*)   (w + 77611520);            //        512
    float*    ab2  = (float*)   (w + 77612032);            //      1,024
    float*    wt0  = (float*)   (w + 77613056);            //     17,152
    float*    wt1  = (float*)   (w + 77630208);            //     16,384
    float*    wt2  = (float*)   (w + 77646592);            //     32,768

    prep_kernel<<<1, 256, 0, stream>>>(W0, W1, W2, wt0, wt1, wt2);
    fps_kernel<<<B_, 256, 0, stream>>>(xyz, out);           // centroids -> output 0
    knn_kernel<<<NQ, 64, 0, stream>>>(xyz, out, nbr);       // reads centroids from output 0

    // layer 0
    l0_kernel<<<2048, 256, 0, stream>>>(xyz, fea, out, nbr, wt0, yT);
    stats_pass<<<64 * 32, 256, 0, stream>>>(yT, part);
    stats_fin<<<1, 64, 0, stream>>>(part, g0, be0, ab0);

    // layer 1 (in-place)
    l1_kernel<<<2048, 256, 0, stream>>>(yT, wt1, ab0);
    stats_pass<<<64 * 32, 256, 0, stream>>>(yT, part);
    stats_fin<<<1, 64, 0, stream>>>(part, g1, be1, ab1);

    // layer 2: stats via recompute, then fused bn+relu+maxpool via recompute
    l2s_kernel<<<dim3(2048, 2), 256, 0, stream>>>(yT, wt2, ab1, part2);
    stats2_fin<<<128, 256, 0, stream>>>(part2, g2, be2, ab2);
    fin_kernel<<<dim3(2048, 2), 256, 0, stream>>>(yT, wt2, ab1, ab2, out);
}

// Round 8
// 1408.465 us; speedup vs baseline: 1.9215x; 1.2564x over previous
//
#include <hip/hip_runtime.h>
#include <cstdint>
#include <cstddef>

typedef unsigned short ushort_t;
typedef unsigned int uint_t;
typedef unsigned long long u64_t;
typedef float v2f __attribute__((ext_vector_type(2)));

#define B_ 16
#define N_ 4096
#define S_ 1024
#define K_ 32
#define NR 524288    // B*S*K rows
#define NQ 16384     // B*S queries

__device__ __forceinline__ float bf2f(ushort_t u) {
    union { uint_t i; float f; } x; x.i = ((uint_t)u) << 16; return x.f;
}
__device__ __forceinline__ ushort_t f2bf(float f) {
    union { float f; uint_t u; } x; x.f = f;
    uint_t u = x.u;
    uint_t r = (u + 0x7fffu + ((u >> 16) & 1u)) >> 16;   // RNE
    return (ushort_t)r;
}

// ---------------------------------------------------------------------------
// DPP wave-64 argmax/argmin over u64 keys (row_shr 1/2/4/8 + bcast15/31),
// result lands in lane 63. Keys unique -> exact total order.
// ---------------------------------------------------------------------------
template <int CTRL>
__device__ __forceinline__ uint_t dppmov(uint_t v, uint_t idt) {
    return (uint_t)__builtin_amdgcn_update_dpp((int)idt, (int)v, CTRL, 0xF, 0xF, false);
}

__device__ __forceinline__ void wave_argmax64(uint_t& hi, uint_t& lo) {
#define STEP_MAX(C) { uint_t nh = dppmov<C>(hi, 0u); uint_t nl = dppmov<C>(lo, 0u); \
    u64_t a = ((u64_t)hi << 32) | lo, bb = ((u64_t)nh << 32) | nl; \
    if (bb > a) { hi = nh; lo = nl; } }
    STEP_MAX(0x111) STEP_MAX(0x112) STEP_MAX(0x114) STEP_MAX(0x118)
    STEP_MAX(0x142) STEP_MAX(0x143)
#undef STEP_MAX
}

__device__ __forceinline__ void wave_argmin64(uint_t& hi, uint_t& lo) {
#define STEP_MIN(C) { uint_t nh = dppmov<C>(hi, 0xFFFFFFFFu); uint_t nl = dppmov<C>(lo, 0xFFFFFFFFu); \
    u64_t a = ((u64_t)hi << 32) | lo, bb = ((u64_t)nh << 32) | nl; \
    if (bb < a) { hi = nh; lo = nl; } }
    STEP_MIN(0x111) STEP_MIN(0x112) STEP_MIN(0x114) STEP_MIN(0x118)
    STEP_MIN(0x142) STEP_MIN(0x143)
#undef STEP_MIN
}

// ---------------------------------------------------------------------------
// prep: weights fp32 -> fp32 transposed. wt0[c][64], wt1[c][64], wt2[c][128]
// ---------------------------------------------------------------------------
__global__ __launch_bounds__(256) void prep_kernel(
        const float* __restrict__ W0, const float* __restrict__ W1,
        const float* __restrict__ W2,
        float* __restrict__ wt0, float* __restrict__ wt1, float* __restrict__ wt2) {
    int tid = threadIdx.x;
    for (int i = tid; i < 64 * 67; i += 256) { int o = i / 67, c = i % 67; wt0[c * 64 + o] = W0[i]; }
    for (int i = tid; i < 64 * 64; i += 256) { int o = i >> 6, c = i & 63; wt1[c * 64 + o] = W1[i]; }
    for (int i = tid; i < 128 * 64; i += 256) { int o = i >> 6, c = i & 63; wt2[c * 128 + o] = W2[i]; }
}

// ---------------------------------------------------------------------------
// FPS: one block (4 waves) per batch, 16 pts/thread packed as float2 pairs
// (v_pk_* fp32: identical IEEE per-lane results, half the instructions).
// u64-key tree + DPP wave argmax + one barrier combine. Key=(dist_bits,~p).
// ---------------------------------------------------------------------------
__global__ __launch_bounds__(256) void fps_kernel(
        const float* __restrict__ xyz, float* __restrict__ out_sxyz) {
    #pragma clang fp contract(off)
    __shared__ float4 pts[N_];
    __shared__ uint2 cand[2][4];
    int b = blockIdx.x, tid = threadIdx.x;
    int wv = tid >> 6, lane = tid & 63;
    const float* base = xyz + (size_t)b * N_ * 3;

    v2f px[8], py[8], pz[8], dist[8];
    #pragma unroll
    for (int t = 0; t < 16; t++) {
        int p = tid + t * 256;
        float x = base[p * 3 + 0];
        float y = base[p * 3 + 1];
        float z = base[p * 3 + 2];
        px[t >> 1][t & 1] = x; py[t >> 1][t & 1] = y; pz[t >> 1][t & 1] = z;
        pts[p] = make_float4(x, y, z, 0.0f);
        dist[t >> 1][t & 1] = 1e10f;
    }
    __syncthreads();

    int far = 0;
    for (int i = 0; i < S_; i++) {
        float4 c = pts[far];                       // ds_read_b128
        if (tid == 0) {
            int qi = b * S_ + i;
            out_sxyz[qi * 3 + 0] = c.x;
            out_sxyz[qi * 3 + 1] = c.y;
            out_sxyz[qi * 3 + 2] = c.z;
        }
        v2f cx = { c.x, c.x }, cy = { c.y, c.y }, cz = { c.z, c.z };
        #pragma unroll
        for (int j = 0; j < 8; j++) {
            v2f dx = px[j] - cx, dy = py[j] - cy, dz = pz[j] - cz;
            v2f d = (dx * dx + dy * dy) + dz * dz;   // mul/add only (ref order)
            dist[j] = __builtin_elementwise_min(dist[j], d);
        }
        // local tree argmax over 16 candidates via u64 keys (exact total order)
        uint_t kh[16], kl[16];
        #pragma unroll
        for (int t = 0; t < 16; t++) {
            kh[t] = __float_as_uint(dist[t >> 1][t & 1]);  // dist>=0: uint order = float order
            kl[t] = ~(uint_t)(tid + t * 256);
        }
        #pragma unroll
        for (int st = 8; st >= 1; st >>= 1) {
            #pragma unroll
            for (int t = 0; t < 8; t++) {
                if (t < st) {
                    u64_t a = ((u64_t)kh[t] << 32) | kl[t];
                    u64_t bb = ((u64_t)kh[t + st] << 32) | kl[t + st];
                    if (bb > a) { kh[t] = kh[t + st]; kl[t] = kl[t + st]; }
                }
            }
        }
        uint_t bh = kh[0], bl = kl[0];
        wave_argmax64(bh, bl);                     // lane 63 has wave winner
        int buf = i & 1;
        if (lane == 63) cand[buf][wv] = make_uint2(bh, bl);
        __syncthreads();
        uint2 c0 = cand[buf][0], c1 = cand[buf][1], c2 = cand[buf][2], c3 = cand[buf][3];
        u64_t best = ((u64_t)c0.x << 32) | c0.y;
        u64_t k1 = ((u64_t)c1.x << 32) | c1.y; if (k1 > best) best = k1;
        u64_t k2 = ((u64_t)c2.x << 32) | c2.y; if (k2 > best) best = k2;
        u64_t k3 = ((u64_t)c3.x << 32) | c3.y; if (k3 > best) best = k3;
        far = (int)((~(uint_t)best) & 4095u);
    }
}

// ---------------------------------------------------------------------------
// KNN: one wave per query -> 32 neighbor indices (unchanged from R7).
// ---------------------------------------------------------------------------
__global__ __launch_bounds__(64) void knn_kernel(
        const float* __restrict__ xyz, const float* __restrict__ qxyz,
        int* __restrict__ nbr) {
    #pragma clang fp contract(off)
    __shared__ uint_t dsm[N_];
    int bs = blockIdx.x;
    int b = bs >> 10;
    int lane = threadIdx.x;
    const float* xb = xyz + (size_t)b * N_ * 3;

    float qx = qxyz[bs * 3 + 0], qy = qxyz[bs * 3 + 1], qz = qxyz[bs * 3 + 2];
    float qq = (qx * qx + qy * qy) + qz * qz;

    uint_t ulv = 0xFFFFFFFFu; int li = 0;
    for (int s = 0; s < 64; s++) {
        int p = s * 64 + lane;
        float x = xb[p * 3 + 0];
        float y = xb[p * 3 + 1];
        float z = xb[p * 3 + 2];
        float pp = (x * x + y * y) + z * z;
        float dt = (qx * x + qy * y) + qz * z;
        float d = (qq + pp) - 2.0f * dt;               // matches ref
        uint_t ub = __float_as_uint(d);
        ub ^= (uint_t)(((int)ub >> 31)) | 0x80000000u; // sortable transform
        dsm[s * 64 + ((lane + s) & 63)] = ub;          // swizzled store
        if (ub < ulv) { ulv = ub; li = p; }
    }
    __syncthreads();

    u64_t mask = 0ull;
    int my_nbr = 0;
    for (int r = 0; r < K_; r++) {
        uint_t hh = ulv, ll = (uint_t)li;
        wave_argmin64(hh, ll);
        int idx = (int)(uint_t)__builtin_amdgcn_readlane((int)ll, 63);
        int glane = idx & 63, srow = idx >> 6;
        if (lane == r) my_nbr = idx;
        if (lane == glane) mask |= 1ull << srow;
        uint_t gml = (uint_t)__builtin_amdgcn_readlane((int)(uint_t)mask, glane);
        uint_t gmh = (uint_t)__builtin_amdgcn_readlane((int)(uint_t)(mask >> 32), glane);
        u64_t gm = ((u64_t)gmh << 32) | gml;
        uint_t cv = ((gm >> lane) & 1ull) ? 0xFFFFFFFFu
                                          : dsm[lane * 64 + ((glane + lane) & 63)];
        uint_t ci = (uint_t)(lane * 64 + glane);
        wave_argmin64(cv, ci);
        uint_t rv = (uint_t)__builtin_amdgcn_readlane((int)cv, 63);
        uint_t ri = (uint_t)__builtin_amdgcn_readlane((int)ci, 63);
        if (lane == glane) { ulv = rv; li = (int)ri; }
    }
    if (lane < K_) nbr[bs * K_ + lane] = my_nbr;
}

// ---------------------------------------------------------------------------
// L0: one thread per row. float4 feature gather + 67x64 FMA -> yT bf16.
// ---------------------------------------------------------------------------
__global__ __launch_bounds__(256) void l0_kernel(
        const float* __restrict__ xyz, const float* __restrict__ fea,
        const float* __restrict__ qxyz, const int* __restrict__ nbr,
        const float* __restrict__ wt0, ushort_t* __restrict__ yT) {
    int row = blockIdx.x * 256 + threadIdx.x;
    int bs = row >> 5, b = bs >> 10;
    int p = nbr[row];
    p = (p < 0) ? 0 : (p > N_ - 1 ? N_ - 1 : p);
    float qx = qxyz[bs * 3 + 0], qy = qxyz[bs * 3 + 1], qz = qxyz[bs * 3 + 2];
    const float* xb = xyz + ((size_t)b * N_ + p) * 3;
    float dx = xb[0] - qx, dy = xb[1] - qy, dz = xb[2] - qz;

    float acc[64];
    #pragma unroll
    for (int o = 0; o < 64; o++)
        acc[o] = fmaf(dz, wt0[128 + o], fmaf(dy, wt0[64 + o], dx * wt0[o]));

    const float4* fr = (const float4*)(fea + ((size_t)b * N_ + p) * 64);
    #pragma unroll 2
    for (int i = 0; i < 16; i++) {
        float4 u = fr[i];
        float ua[4] = { u.x, u.y, u.z, u.w };
        #pragma unroll
        for (int j = 0; j < 4; j++) {
            const float* w = wt0 + (3 + i * 4 + j) * 64;
            #pragma unroll
            for (int o = 0; o < 64; o++) acc[o] = fmaf(ua[j], w[o], acc[o]);
        }
    }
    #pragma unroll
    for (int o = 0; o < 64; o++)
        yT[(size_t)o * NR + row] = f2bf(acc[o]);
}

// ---------------------------------------------------------------------------
// BN stats over 64-channel channel-major bf16 buffer (vectorized).
// ---------------------------------------------------------------------------
__global__ __launch_bounds__(256) void stats_pass(
        const ushort_t* __restrict__ y, float* __restrict__ part) {
    int cb = blockIdx.x;
    int c = cb >> 5, ch = cb & 31;
    const uint4* src = (const uint4*)(y + (size_t)c * NR + (size_t)ch * 16384);
    float s = 0.0f, q = 0.0f;
    for (int i = threadIdx.x; i < 2048; i += 256) {
        uint4 u = src[i];
        uint_t ua[4] = { u.x, u.y, u.z, u.w };
        #pragma unroll
        for (int j = 0; j < 4; j++) {
            float v0 = bf2f((ushort_t)(ua[j] & 0xffffu));
            float v1 = bf2f((ushort_t)(ua[j] >> 16));
            s += v0; q = fmaf(v0, v0, q);
            s += v1; q = fmaf(v1, v1, q);
        }
    }
    __shared__ float ls[256], lq[256];
    int tid = threadIdx.x;
    ls[tid] = s; lq[tid] = q;
    __syncthreads();
    for (int off = 128; off >= 1; off >>= 1) {
        if (tid < off) { ls[tid] += ls[tid + off]; lq[tid] += lq[tid + off]; }
        __syncthreads();
    }
    if (tid == 0) { part[cb * 2 + 0] = ls[0]; part[cb * 2 + 1] = lq[0]; }
}

__global__ __launch_bounds__(64) void stats_fin(
        const float* __restrict__ part, const float* __restrict__ g,
        const float* __restrict__ be, float* __restrict__ ab) {
    int o = threadIdx.x;  // C = 64
    double s = 0.0, q = 0.0;
    for (int ch = 0; ch < 32; ch++) {
        s += (double)part[(o * 32 + ch) * 2 + 0];
        q += (double)part[(o * 32 + ch) * 2 + 1];
    }
    double mu = s / (double)NR;
    double var = q / (double)NR - mu * mu;
    if (var < 0.0) var = 0.0;
    double a = (double)g[o] / sqrt(var + 1e-5);
    ab[o]      = (float)a;
    ab[64 + o] = (float)((double)be[o] - mu * a);
}

// ---------------------------------------------------------------------------
// L1: in-place on yT. Each thread owns one row.
// ---------------------------------------------------------------------------
__global__ __launch_bounds__(256) void l1_kernel(
        ushort_t* yT, const float* __restrict__ wt1, const float* __restrict__ ab) {
    int row = blockIdx.x * 256 + threadIdx.x;
    float xv[64];
    #pragma unroll
    for (int c = 0; c < 64; c++)
        xv[c] = fmaxf(fmaf(bf2f(yT[(size_t)c * NR + row]), ab[c], ab[64 + c]), 0.0f);
    float acc[64];
    #pragma unroll
    for (int o = 0; o < 64; o++) acc[o] = 0.0f;
    #pragma unroll 4
    for (int c = 0; c < 64; c++) {
        const float* w = wt1 + c * 64;
        #pragma unroll
        for (int o = 0; o < 64; o++) acc[o] = fmaf(xv[c], w[o], acc[o]);
    }
    #pragma unroll
    for (int o = 0; o < 64; o++)
        yT[(size_t)o * NR + row] = f2bf(acc[o]);
}

// ---------------------------------------------------------------------------
// L2 stats + EARLY MAXPOOL: recompute y2 rows, per-channel butterfly sums
// (s,q) -> block partials, and per-query max M (BN2 scale a>0: maxpool
// commutes with BN+ReLU, so fin only needs M). LDS-staged coalesced writes.
// part2s layout: [2(s,q)][128][2048 blocks] fp32. M: [16384][128] fp32.
// ---------------------------------------------------------------------------
__global__ __launch_bounds__(256) void l2s_kernel(
        const ushort_t* __restrict__ yT, const float* __restrict__ wt2,
        const float* __restrict__ ab1, float* __restrict__ part2s,
        float* __restrict__ M) {
    int bx = blockIdx.x, half = blockIdx.y;
    int tid = threadIdx.x;
    int row = bx * 256 + tid;
    int lane = tid & 63, wv = tid >> 6;
    float xv[64];
    #pragma unroll
    for (int c = 0; c < 64; c++)
        xv[c] = fmaxf(fmaf(bf2f(yT[(size_t)c * NR + row]), ab1[c], ab1[64 + c]), 0.0f);
    float acc[64];
    #pragma unroll
    for (int o = 0; o < 64; o++) acc[o] = 0.0f;
    const float* w = wt2 + half * 64;
    #pragma unroll 4
    for (int c = 0; c < 64; c++) {
        const float* wr = w + c * 128;
        #pragma unroll
        for (int o = 0; o < 64; o++) acc[o] = fmaf(xv[c], wr[o], acc[o]);
    }
    __shared__ float Msm[4][2][64];
    __shared__ float Ssm[4][64], Qsm[4][64];
    #pragma unroll 2
    for (int o = 0; o < 64; o++) {
        float v = acc[o];
        float m = v;
        #pragma unroll
        for (int mo = 1; mo <= 16; mo <<= 1) m = fmaxf(m, __shfl_xor(m, mo));
        float s = v, q = v * v;
        #pragma unroll
        for (int mo = 1; mo <= 32; mo <<= 1) { s += __shfl_xor(s, mo); q += __shfl_xor(q, mo); }
        if (lane == 0)  { Msm[wv][0][o] = m; Ssm[wv][o] = s; Qsm[wv][o] = q; }
        if (lane == 32) { Msm[wv][1][o] = m; }
    }
    __syncthreads();
    // M epilogue: 512 entries, coalesced
    #pragma unroll
    for (int r = 0; r < 2; r++) {
        int e = tid + r * 256;
        int ewv = e >> 7, eq = (e >> 6) & 1, eo = e & 63;
        M[(size_t)(bx * 8 + ewv * 2 + eq) * 128 + half * 64 + eo] = Msm[ewv][eq][eo];
    }
    // s,q block partials
    if (tid < 64) {
        float s = Ssm[0][tid] + Ssm[1][tid] + Ssm[2][tid] + Ssm[3][tid];
        part2s[(size_t)(half * 64 + tid) * 2048 + bx] = s;
    } else if (tid < 128) {
        int ch = tid - 64;
        float q = Qsm[0][ch] + Qsm[1][ch] + Qsm[2][ch] + Qsm[3][ch];
        part2s[(size_t)128 * 2048 + (size_t)(half * 64 + ch) * 2048 + bx] = q;
    }
}

__global__ __launch_bounds__(256) void stats2_fin(
        const float* __restrict__ part2s, const float* __restrict__ g,
        const float* __restrict__ be, float* __restrict__ ab2) {
    int og = blockIdx.x;  // 0..127
    float s = 0.0f, q = 0.0f;
    for (int col = threadIdx.x; col < 2048; col += 256) {
        s += part2s[(size_t)og * 2048 + col];
        q += part2s[(size_t)128 * 2048 + (size_t)og * 2048 + col];
    }
    __shared__ float ls[256], lq[256];
    int tid = threadIdx.x;
    ls[tid] = s; lq[tid] = q;
    __syncthreads();
    for (int off = 128; off >= 1; off >>= 1) {
        if (tid < off) { ls[tid] += ls[tid + off]; lq[tid] += lq[tid + off]; }
        __syncthreads();
    }
    if (tid == 0) {
        double mu = (double)ls[0] / (double)NR;
        double var = (double)lq[0] / (double)NR - mu * mu;
        if (var < 0.0) var = 0.0;
        double a = (double)g[og] / sqrt(var + 1e-5);
        ab2[og]       = (float)a;
        ab2[128 + og] = (float)((double)be[og] - mu * a);
    }
}

// ---------------------------------------------------------------------------
// fin: trivial map out = relu(a*M + c)  (valid because a = g/sqrt(var) > 0).
// ---------------------------------------------------------------------------
__global__ __launch_bounds__(256) void fin_kernel(
        const float* __restrict__ M, const float* __restrict__ ab2,
        float* __restrict__ out) {
    int idx = blockIdx.x * 256 + threadIdx.x;   // 0 .. 2097151
    int og = idx & 127;
    out[49152 + idx] = fmaxf(fmaf(M[idx], ab2[og], ab2[128 + og]), 0.0f);
}

// ---------------------------------------------------------------------------
extern "C" void kernel_launch(void* const* d_in, const int* in_sizes, int n_in,
                              void* d_out, int out_size, void* d_ws, size_t ws_size,
                              hipStream_t stream) {
    const float* xyz = (const float*)d_in[0];
    const float* fea = (const float*)d_in[1];
    const float* W0  = (const float*)d_in[2];
    const float* g0  = (const float*)d_in[4];
    const float* be0 = (const float*)d_in[5];
    const float* W1  = (const float*)d_in[6];
    const float* g1  = (const float*)d_in[8];
    const float* be1 = (const float*)d_in[9];
    const float* W2  = (const float*)d_in[10];
    const float* g2  = (const float*)d_in[12];
    const float* be2 = (const float*)d_in[13];
    float* out = (float*)d_out;

    char* w = (char*)d_ws;
    // total footprint ~74.1 MB (identical to proven R7 layout)
    ushort_t* yT    = (ushort_t*)(w);                      // 67,108,864
    int*      nbr   = (int*)     (w + 67108864);           //  2,097,152 (dead after l0)
    float*    part2s= (float*)   (w + 67108864);           //  2,097,152 (l2s partials, aliases nbr)
    float*    part  = (float*)   (w + 69206016);           //     16,384
    float*    M     = (float*)   (w + 69222400);           //  8,388,608 (old part2 slot)
    float*    ab0   = (float*)   (w + 77611008);           //        512
    float*    ab1   = (float*)   (w + 77611520);           //        512
    float*    ab2   = (float*)   (w + 77612032);           //      1,024
    float*    wt0   = (float*)   (w + 77613056);           //     17,152
    float*    wt1   = (float*)   (w + 77630208);           //     16,384
    float*    wt2   = (float*)   (w + 77646592);           //     32,768

    prep_kernel<<<1, 256, 0, stream>>>(W0, W1, W2, wt0, wt1, wt2);
    fps_kernel<<<B_, 256, 0, stream>>>(xyz, out);           // centroids -> output 0
    knn_kernel<<<NQ, 64, 0, stream>>>(xyz, out, nbr);

    // layer 0
    l0_kernel<<<2048, 256, 0, stream>>>(xyz, fea, out, nbr, wt0, yT);
    stats_pass<<<64 * 32, 256, 0, stream>>>(yT, part);
    stats_fin<<<1, 64, 0, stream>>>(part, g0, be0, ab0);

    // layer 1 (in-place)
    l1_kernel<<<2048, 256, 0, stream>>>(yT, wt1, ab0);
    stats_pass<<<64 * 32, 256, 0, stream>>>(yT, part);
    stats_fin<<<1, 64, 0, stream>>>(part, g1, be1, ab1);

    // layer 2: GEMM once (stats + early maxpool), then trivial fin
    l2s_kernel<<<dim3(2048, 2), 256, 0, stream>>>(yT, wt2, ab1, part2s, M);
    stats2_fin<<<128, 256, 0, stream>>>(part2s, g2, be2, ab2);
    fin_kernel<<<8192, 256, 0, stream>>>(M, ab2, out);
}